// Round 22
// baseline (46.627 us; speedup 1.0000x reference)
//
#include <hip/hip_runtime.h>

// Reck-mesh MZI layer, N=256, BATCH=4096.
// out[b][i] = sum_j x[b][j] * Re(e^{i phi_ext[i]} U[i][j])
// Depth-split: U = A * B (steps 256..511 / 0..255), 512 half-depth chains.
// R22 = R17 (best, 43.8us) + build block remap for L1 request-merging:
// build is L2 request-THROUGHPUT bound (R21's perfect prefetch = null). With
// grid(256,2), the 2 waves/CU read DISJOINT halves (no L1 reuse). Remap
// h=(b>>7)&1, j=(b&127)+((b>>8)<<7): blocks b and b+256 (same CU under
// round-robin dispatch) now read the SAME half in near-lockstep -> second
// wave's line requests merge in L1 -> L2 requests halve.
//   coeff  -> cf3 stream                 [R17 verbatim]
//   build  -> At, Bt                     [R17 verbatim + remap]
//   mergebf-> Wb[i][j]                   [R17 verbatim]
//   gemm   -> out = x @ Wb^T bf16 MFMA   [R17 verbatim]

#define NN 256
#define NB 4096

typedef float f32x4 __attribute__((ext_vector_type(4)));
typedef short bf16x8 __attribute__((ext_vector_type(8)));

// ws layout:
//  [0, 512K)     At  float2[256][256]   (At[c][r] = A[r][c])
//  [512K, 1M)    Bt  float2[256][256]
//  [1M, 2M)      cf3: 64 groups x 16 slots x 64 lanes x 16B
//  [2M, 2.125M)  Wb  bf16[256][256]
#define WS_AT_OFF   0u
#define WS_BT_OFF   (512u * 1024u)
#define WS_CF_OFF   (1u << 20)
#define WS_WB_OFF   (2u << 20)

__device__ __forceinline__ unsigned short f2bf(float f) {   // RNE float->bf16
    unsigned u = __builtin_bit_cast(unsigned, f);
    unsigned r = (u + 0x7FFFu + ((u >> 16) & 1u)) >> 16;
    return (unsigned short)r;
}

// ---------------- coefficient stream (unchanged) ----------------
__global__ __launch_bounds__(64) void coeff2_kernel(const float* __restrict__ theta,
                                                    const float* __restrict__ phi,
                                                    f32x4* __restrict__ cf3) {
    const int t = blockIdx.x;        // 0..511
    const int l = threadIdx.x;
    const int g = t >> 3, jj = t & 7;
    const int pA = (t & 1) ? (4 * l + 1) : (4 * l);
#pragma unroll
    for (int s = 0; s < 2; ++s) {
        int p = pA + 2 * s;
        f32x4 v = {1.f, 0.f, 0.f, 0.f};              // identity rotation
        if (p <= t && p + t <= 508) {                // active op at (t,p)
            int L = (t - p) >> 1;                    // layer 0..254
            int k = ((L * (511 - L)) >> 1) + p;      // off(L) = L*(511-L)/2
            float st, ct, sp, cp;
            __sincosf(theta[k], &st, &ct);
            __sincosf(phi[k], &sp, &cp);
            v = (f32x4){ct, st * cp, st * sp, 0.f};
        }
        cf3[(g * 16 + 8 * s + jj) * 64 + l] = v;
    }
}

// ---------------- build A/B columns: 1 wave = 1 chain, reg-only [R13] -------
__device__ __forceinline__ float dpp_up1(float x) {   // lane i <- lane i-1, lane0 -> 0
    int r = __builtin_amdgcn_update_dpp(0, __builtin_bit_cast(int, x), 0x138, 0xF, 0xF, true);
    return __builtin_bit_cast(float, r);
}
__device__ __forceinline__ float dpp_dn1(float x) {   // lane i <- lane i+1, lane63 -> 0
    int r = __builtin_amdgcn_update_dpp(0, __builtin_bit_cast(int, x), 0x130, 0xF, 0xF, true);
    return __builtin_bit_cast(float, r);
}

__device__ __forceinline__ void rot2(float& ar, float& ai, float& br, float& bi, f32x4 co) {
    float c = co.x, sx = co.y, sy = co.z;
    float nar = c * ar - (sx * br + sy * bi);
    float nai = c * ai - (sx * bi - sy * br);
    float nbr = sx * ar - sy * ai + c * br;
    float nbi = sx * ai + sy * ar + c * bi;
    ar = nar; ai = nai; br = nbr; bi = nbi;
}

// compiler+scheduler fence: pins already-issued loads (no instructions emitted)
__device__ __forceinline__ void fence() {
    asm volatile("" ::: "memory");
    __builtin_amdgcn_sched_barrier(0);
}

__global__ __launch_bounds__(64, 1) void build_kernel(const f32x4* __restrict__ cf3,
                                                      float2* __restrict__ Ata,
                                                      float2* __restrict__ Btb) {
    const int l  = threadIdx.x;
    const int r0 = 4 * l;
    // Remap so blocks b and b+256 (same CU under round-robin dispatch) get the
    // SAME half h -> their identical-group reads merge in L1.
    const int b  = blockIdx.x;               // 0..511
    const int h  = (b >> 7) & 1;             // 0: steps 0..255 (B), 1: 256..511 (A)
    const int j  = (b & 127) + ((b >> 8) << 7);   // column 0..255
    const int G0 = 32 * h;
    float2* dst = (h ? Ata : Btb) + (size_t)j * NN;

    float ur0 = (r0 + 0 == j) ? 1.f : 0.f, ui0 = 0.f;
    float ur1 = (r0 + 1 == j) ? 1.f : 0.f, ui1 = 0.f;
    float ur2 = (r0 + 2 == j) ? 1.f : 0.f, ui2 = 0.f;
    float ur3 = (r0 + 3 == j) ? 1.f : 0.f, ui3 = 0.f;
    const float lane0_one = (l == 0) ? 1.f : 0.f;

    f32x4 RA[16], RB[16];    // register double-buffer (64 VGPR each)

    auto loadgrp = [&](int g, f32x4 (&R)[16]) {
        const f32x4* sp = cf3 + (size_t)g * 1024 + l;
#pragma unroll
        for (int s = 0; s < 16; ++s) R[s] = sp[s * 64];
    };

    auto compute = [&](const f32x4 (&R)[16]) {       // 8 steps, VALU+DPP only
#pragma unroll
        for (int jj = 0; jj < 8; ++jj) {
            if ((jj & 1) == 0) {
                rot2(ur0, ui0, ur1, ui1, R[jj]);        // p = 4l
                rot2(ur2, ui2, ur3, ui3, R[8 + jj]);    // p = 4l+2
            } else {
                float d0r = dpp_dn1(ur0), d0i = dpp_dn1(ui0);  // lane l+1 row 4l+4
                float u3r = dpp_up1(ur3), u3i = dpp_up1(ui3);  // lane l-1 row 4l-1
                f32x4 cb = R[8 + jj];
                float cx = dpp_up1(cb.x) + lane0_one;   // C = lane l-1's B (lane0: id)
                float cy = dpp_up1(cb.y);
                float cz = dpp_up1(cb.z);
                rot2(ur1, ui1, ur2, ui2, R[jj]);        // p = 4l+1
                float n3r = cb.x * ur3 - (cb.y * d0r + cb.z * d0i);   // p = 4l+3
                float n3i = cb.x * ui3 - (cb.y * d0i - cb.z * d0r);
                float n0r = cy * u3r - cz * u3i + cx * ur0;           // p = 4l-1
                float n0i = cy * u3i + cz * u3r + cx * ui0;
                ur3 = n3r; ui3 = n3i; ur0 = n0r; ui0 = n0i;
            }
        }
    };

    loadgrp(G0 + 0, RA);
    fence();
    for (int g = 0; g < 32; g += 2) {
        if (g + 1 < 32) loadgrp(G0 + g + 1, RB);   // in flight during compute(RA)
        fence();
        compute(RA);
        if (g + 2 < 32) loadgrp(G0 + g + 2, RA);
        fence();
        compute(RB);
    }

    // store column j as row j of the transposed half: coalesced 32B/lane
    *(float4*)(dst + r0)     = make_float4(ur0, ui0, ur1, ui1);
    *(float4*)(dst + r0 + 2) = make_float4(ur2, ui2, ur3, ui3);
}

// ---------------- mergebf: Wb[i][j] = bf16(Re(e^{i phi_i} sum_k At[k][i] Bt[j][k]))
__global__ __launch_bounds__(256) void mergebf_kernel(const float2* __restrict__ At,
                                                      const float2* __restrict__ Bt,
                                                      const float* __restrict__ phi_ext,
                                                      unsigned short* __restrict__ Wb) {
    __shared__ float2 Ats[64][16];   // [k][i]
    __shared__ float2 Bts[16][64];   // [j][k]

    const int t  = threadIdx.x;
    const int i0 = blockIdx.x * 16;
    const int j0 = blockIdx.y * 16;
    const int ti = t & 15;
    const int tj = t >> 4;

    float sr = 0.f, si = 0.f;

    for (int kc = 0; kc < NN; kc += 64) {
#pragma unroll
        for (int rep = 0; rep < 2; ++rep) {
            int e = t + rep * 256;
            int k = e >> 3, f = e & 7;
            float4 v = *(const float4*)(At + (size_t)(kc + k) * NN + i0 + 2 * f);
            Ats[k][2 * f]     = make_float2(v.x, v.y);
            Ats[k][2 * f + 1] = make_float2(v.z, v.w);
        }
#pragma unroll
        for (int rep = 0; rep < 2; ++rep) {
            int e = t + rep * 256;
            int j = e >> 5, q = e & 31;
            float4 w = *(const float4*)(Bt + (size_t)(j0 + j) * NN + kc + 2 * q);
            Bts[j][2 * q]     = make_float2(w.x, w.y);
            Bts[j][2 * q + 1] = make_float2(w.z, w.w);
        }
        __syncthreads();
#pragma unroll 8
        for (int k = 0; k < 64; ++k) {
            float2 a = Ats[k][ti];
            float2 b = Bts[tj][k];
            sr += a.x * b.x - a.y * b.y;
            si += a.x * b.y + a.y * b.x;
        }
        __syncthreads();
    }

    float sp, cp;
    __sincosf(phi_ext[i0 + ti], &sp, &cp);
    Wb[(size_t)(i0 + ti) * NN + j0 + tj] = f2bf(cp * sr - sp * si);
}

// ---------------- out = x @ Wb^T via MFMA bf16; x converted in staging ------
__global__ __launch_bounds__(256) void gemm_kernel(const float* __restrict__ x,
                                                   const unsigned short* __restrict__ Wb,
                                                   float* __restrict__ out) {
    __shared__ unsigned short Xs[64][72];
    __shared__ unsigned short Ws[64][72];

    const int tid = threadIdx.x;
    const int l   = tid & 63;
    const int wid = tid >> 6;
    const int wm  = wid >> 1, wn = wid & 1;
    const int b0  = blockIdx.x * 64;
    const int i0  = blockIdx.y * 64;

    const int srow = tid >> 2;            // staging: row 0..63
    const int sseg = (tid & 3) * 2;       // 2 of 8 8-elem segments

    f32x4 acc[2][2] = {{{0.f, 0.f, 0.f, 0.f}, {0.f, 0.f, 0.f, 0.f}},
                       {{0.f, 0.f, 0.f, 0.f}, {0.f, 0.f, 0.f, 0.f}}};

    const int fr = l & 15;
    const int kg = (l >> 4) * 8;

    for (int k0 = 0; k0 < NN; k0 += 64) {
        const float* xrow = x + (size_t)(b0 + srow) * NN + k0 + sseg * 8;
        float4 a = *(const float4*)(xrow);
        float4 b = *(const float4*)(xrow + 4);
        float4 c = *(const float4*)(xrow + 8);
        float4 d = *(const float4*)(xrow + 12);
        uint4 xv, xv2;
        xv.x  = (unsigned)f2bf(a.x) | ((unsigned)f2bf(a.y) << 16);
        xv.y  = (unsigned)f2bf(a.z) | ((unsigned)f2bf(a.w) << 16);
        xv.z  = (unsigned)f2bf(b.x) | ((unsigned)f2bf(b.y) << 16);
        xv.w  = (unsigned)f2bf(b.z) | ((unsigned)f2bf(b.w) << 16);
        xv2.x = (unsigned)f2bf(c.x) | ((unsigned)f2bf(c.y) << 16);
        xv2.y = (unsigned)f2bf(c.z) | ((unsigned)f2bf(c.w) << 16);
        xv2.z = (unsigned)f2bf(d.x) | ((unsigned)f2bf(d.y) << 16);
        xv2.w = (unsigned)f2bf(d.z) | ((unsigned)f2bf(d.w) << 16);
        uint4 wv  = *(const uint4*)(Wb + (size_t)(i0 + srow) * NN + k0 + sseg * 8);
        uint4 wv2 = *(const uint4*)(Wb + (size_t)(i0 + srow) * NN + k0 + (sseg + 1) * 8);
        *(uint4*)&Xs[srow][sseg * 8]       = xv;
        *(uint4*)&Ws[srow][sseg * 8]       = wv;
        *(uint4*)&Xs[srow][(sseg + 1) * 8] = xv2;
        *(uint4*)&Ws[srow][(sseg + 1) * 8] = wv2;
        __syncthreads();

#pragma unroll
        for (int ks = 0; ks < 2; ++ks) {
            bf16x8 a0  = *(const bf16x8*)&Xs[wm * 32 + fr][ks * 32 + kg];
            bf16x8 a1  = *(const bf16x8*)&Xs[wm * 32 + 16 + fr][ks * 32 + kg];
            bf16x8 bb0 = *(const bf16x8*)&Ws[wn * 32 + fr][ks * 32 + kg];
            bf16x8 bb1 = *(const bf16x8*)&Ws[wn * 32 + 16 + fr][ks * 32 + kg];
            acc[0][0] = __builtin_amdgcn_mfma_f32_16x16x32_bf16(a0, bb0, acc[0][0], 0, 0, 0);
            acc[0][1] = __builtin_amdgcn_mfma_f32_16x16x32_bf16(a0, bb1, acc[0][1], 0, 0, 0);
            acc[1][0] = __builtin_amdgcn_mfma_f32_16x16x32_bf16(a1, bb0, acc[1][0], 0, 0, 0);
            acc[1][1] = __builtin_amdgcn_mfma_f32_16x16x32_bf16(a1, bb1, acc[1][1], 0, 0, 0);
        }
        __syncthreads();
    }

    const int drow = (l >> 4) * 4;
    const int dcol = l & 15;
#pragma unroll
    for (int mf = 0; mf < 2; ++mf)
#pragma unroll
        for (int nf = 0; nf < 2; ++nf) {
            float* op = out + (size_t)(b0 + wm * 32 + mf * 16 + drow) * NN
                      + i0 + wn * 32 + nf * 16 + dcol;
#pragma unroll
            for (int r = 0; r < 4; ++r) op[(size_t)r * NN] = acc[mf][nf][r];
        }
}

extern "C" void kernel_launch(void* const* d_in, const int* in_sizes, int n_in,
                              void* d_out, int out_size, void* d_ws, size_t ws_size,
                              hipStream_t stream) {
    const float* x     = (const float*)d_in[0];
    const float* theta = (const float*)d_in[1];
    const float* phi_i = (const float*)d_in[2];
    const float* phi_e = (const float*)d_in[3];
    float* out = (float*)d_out;

    float2* At  = (float2*)((char*)d_ws + WS_AT_OFF);
    float2* Bt  = (float2*)((char*)d_ws + WS_BT_OFF);
    f32x4*  cf3 = (f32x4*)((char*)d_ws + WS_CF_OFF);
    unsigned short* Wb = (unsigned short*)((char*)d_ws + WS_WB_OFF);

    coeff2_kernel<<<dim3(512), dim3(64), 0, stream>>>(theta, phi_i, cf3);
    build_kernel<<<dim3(512), dim3(64), 0, stream>>>(cf3, At, Bt);
    mergebf_kernel<<<dim3(16, 16), dim3(256), 0, stream>>>(At, Bt, phi_e, Wb);
    gemm_kernel<<<dim3(NB / 64, NN / 64), dim3(256), 0, stream>>>(x, Wb, out);
}

// Round 23
// 43.728 us; speedup vs baseline: 1.0663x; 1.0663x over previous
//
#include <hip/hip_runtime.h>

// Reck-mesh MZI layer, N=256, BATCH=4096.
// out[b][i] = sum_j x[b][j] * Re(e^{i phi_ext[i]} U[i][j])
// Depth-split: U = A * B (steps 256..511 / 0..255), 512 independent half-depth
// column chains (wavefront t = 2L+p, disjoint row pairs per step).
// R23 = R17 exact revert (best verified: 43.8us). Ten build experiments
// (prefetch depth, barrier styles, occupancy, replication, masking, asm
// pinning, L1 pairing) all null/negative: build sits on an L2->L1 broadcast
// return-bandwidth floor (~64 waves/XCD x 16KB/group). Practical plateau.
//   coeff  -> cf3 stream
//   build  -> At, Bt (single-wave reg double-buffer, 512 blocks)
//   mergebf-> Wb[i][j] = bf16(Re(e^{i phi_i} sum_k At[k][i] Bt[j][k]))
//   gemm   -> out = x @ Wb^T via bf16 MFMA, x converted during staging

#define NN 256
#define NB 4096

typedef float f32x4 __attribute__((ext_vector_type(4)));
typedef short bf16x8 __attribute__((ext_vector_type(8)));

// ws layout:
//  [0, 512K)     At  float2[256][256]   (At[c][r] = A[r][c])
//  [512K, 1M)    Bt  float2[256][256]
//  [1M, 2M)      cf3: 64 groups x 16 slots x 64 lanes x 16B
//  [2M, 2.125M)  Wb  bf16[256][256]
#define WS_AT_OFF   0u
#define WS_BT_OFF   (512u * 1024u)
#define WS_CF_OFF   (1u << 20)
#define WS_WB_OFF   (2u << 20)

__device__ __forceinline__ unsigned short f2bf(float f) {   // RNE float->bf16
    unsigned u = __builtin_bit_cast(unsigned, f);
    unsigned r = (u + 0x7FFFu + ((u >> 16) & 1u)) >> 16;
    return (unsigned short)r;
}

// ---------------- coefficient stream ----------------
__global__ __launch_bounds__(64) void coeff2_kernel(const float* __restrict__ theta,
                                                    const float* __restrict__ phi,
                                                    f32x4* __restrict__ cf3) {
    const int t = blockIdx.x;        // 0..511
    const int l = threadIdx.x;
    const int g = t >> 3, jj = t & 7;
    const int pA = (t & 1) ? (4 * l + 1) : (4 * l);
#pragma unroll
    for (int s = 0; s < 2; ++s) {
        int p = pA + 2 * s;
        f32x4 v = {1.f, 0.f, 0.f, 0.f};              // identity rotation
        if (p <= t && p + t <= 508) {                // active op at (t,p)
            int L = (t - p) >> 1;                    // layer 0..254
            int k = ((L * (511 - L)) >> 1) + p;      // off(L) = L*(511-L)/2
            float st, ct, sp, cp;
            __sincosf(theta[k], &st, &ct);
            __sincosf(phi[k], &sp, &cp);
            v = (f32x4){ct, st * cp, st * sp, 0.f};
        }
        cf3[(g * 16 + 8 * s + jj) * 64 + l] = v;
    }
}

// ---------------- build A/B columns: 1 wave = 1 chain, reg-only -------------
__device__ __forceinline__ float dpp_up1(float x) {   // lane i <- lane i-1, lane0 -> 0
    int r = __builtin_amdgcn_update_dpp(0, __builtin_bit_cast(int, x), 0x138, 0xF, 0xF, true);
    return __builtin_bit_cast(float, r);
}
__device__ __forceinline__ float dpp_dn1(float x) {   // lane i <- lane i+1, lane63 -> 0
    int r = __builtin_amdgcn_update_dpp(0, __builtin_bit_cast(int, x), 0x130, 0xF, 0xF, true);
    return __builtin_bit_cast(float, r);
}

__device__ __forceinline__ void rot2(float& ar, float& ai, float& br, float& bi, f32x4 co) {
    float c = co.x, sx = co.y, sy = co.z;
    float nar = c * ar - (sx * br + sy * bi);
    float nai = c * ai - (sx * bi - sy * br);
    float nbr = sx * ar - sy * ai + c * br;
    float nbi = sx * ai + sy * ar + c * bi;
    ar = nar; ai = nai; br = nbr; bi = nbi;
}

// compiler+scheduler fence: pins already-issued loads (no instructions emitted)
__device__ __forceinline__ void fence() {
    asm volatile("" ::: "memory");
    __builtin_amdgcn_sched_barrier(0);
}

__global__ __launch_bounds__(64, 1) void build_kernel(const f32x4* __restrict__ cf3,
                                                      float2* __restrict__ Ata,
                                                      float2* __restrict__ Btb) {
    const int l  = threadIdx.x;
    const int r0 = 4 * l;
    const int j  = blockIdx.x;           // column 0..255
    const int h  = blockIdx.y;           // 0: steps 0..255 (B), 1: 256..511 (A)
    const int G0 = 32 * h;
    float2* dst = (h ? Ata : Btb) + (size_t)j * NN;

    float ur0 = (r0 + 0 == j) ? 1.f : 0.f, ui0 = 0.f;
    float ur1 = (r0 + 1 == j) ? 1.f : 0.f, ui1 = 0.f;
    float ur2 = (r0 + 2 == j) ? 1.f : 0.f, ui2 = 0.f;
    float ur3 = (r0 + 3 == j) ? 1.f : 0.f, ui3 = 0.f;
    const float lane0_one = (l == 0) ? 1.f : 0.f;

    f32x4 RA[16], RB[16];    // register double-buffer (64 VGPR each)

    auto loadgrp = [&](int g, f32x4 (&R)[16]) {
        const f32x4* sp = cf3 + (size_t)g * 1024 + l;
#pragma unroll
        for (int s = 0; s < 16; ++s) R[s] = sp[s * 64];
    };

    auto compute = [&](const f32x4 (&R)[16]) {       // 8 steps, VALU+DPP only
#pragma unroll
        for (int jj = 0; jj < 8; ++jj) {
            if ((jj & 1) == 0) {
                rot2(ur0, ui0, ur1, ui1, R[jj]);        // p = 4l
                rot2(ur2, ui2, ur3, ui3, R[8 + jj]);    // p = 4l+2
            } else {
                float d0r = dpp_dn1(ur0), d0i = dpp_dn1(ui0);  // lane l+1 row 4l+4
                float u3r = dpp_up1(ur3), u3i = dpp_up1(ui3);  // lane l-1 row 4l-1
                f32x4 cb = R[8 + jj];
                float cx = dpp_up1(cb.x) + lane0_one;   // C = lane l-1's B (lane0: id)
                float cy = dpp_up1(cb.y);
                float cz = dpp_up1(cb.z);
                rot2(ur1, ui1, ur2, ui2, R[jj]);        // p = 4l+1
                float n3r = cb.x * ur3 - (cb.y * d0r + cb.z * d0i);   // p = 4l+3
                float n3i = cb.x * ui3 - (cb.y * d0i - cb.z * d0r);
                float n0r = cy * u3r - cz * u3i + cx * ur0;           // p = 4l-1
                float n0i = cy * u3i + cz * u3r + cx * ui0;
                ur3 = n3r; ui3 = n3i; ur0 = n0r; ui0 = n0i;
            }
        }
    };

    loadgrp(G0 + 0, RA);
    fence();
    for (int g = 0; g < 32; g += 2) {
        if (g + 1 < 32) loadgrp(G0 + g + 1, RB);   // in flight during compute(RA)
        fence();
        compute(RA);
        if (g + 2 < 32) loadgrp(G0 + g + 2, RA);
        fence();
        compute(RB);
    }

    // store column j as row j of the transposed half: coalesced 32B/lane
    *(float4*)(dst + r0)     = make_float4(ur0, ui0, ur1, ui1);
    *(float4*)(dst + r0 + 2) = make_float4(ur2, ui2, ur3, ui3);
}

// ---------------- mergebf: Wb[i][j] = bf16(Re(e^{i phi_i} sum_k At[k][i] Bt[j][k]))
__global__ __launch_bounds__(256) void mergebf_kernel(const float2* __restrict__ At,
                                                      const float2* __restrict__ Bt,
                                                      const float* __restrict__ phi_ext,
                                                      unsigned short* __restrict__ Wb) {
    __shared__ float2 Ats[64][16];   // [k][i]
    __shared__ float2 Bts[16][64];   // [j][k]

    const int t  = threadIdx.x;
    const int i0 = blockIdx.x * 16;
    const int j0 = blockIdx.y * 16;
    const int ti = t & 15;
    const int tj = t >> 4;

    float sr = 0.f, si = 0.f;

    for (int kc = 0; kc < NN; kc += 64) {
#pragma unroll
        for (int rep = 0; rep < 2; ++rep) {
            int e = t + rep * 256;
            int k = e >> 3, f = e & 7;
            float4 v = *(const float4*)(At + (size_t)(kc + k) * NN + i0 + 2 * f);
            Ats[k][2 * f]     = make_float2(v.x, v.y);
            Ats[k][2 * f + 1] = make_float2(v.z, v.w);
        }
#pragma unroll
        for (int rep = 0; rep < 2; ++rep) {
            int e = t + rep * 256;
            int j = e >> 5, q = e & 31;
            float4 w = *(const float4*)(Bt + (size_t)(j0 + j) * NN + kc + 2 * q);
            Bts[j][2 * q]     = make_float2(w.x, w.y);
            Bts[j][2 * q + 1] = make_float2(w.z, w.w);
        }
        __syncthreads();
#pragma unroll 8
        for (int k = 0; k < 64; ++k) {
            float2 a = Ats[k][ti];
            float2 b = Bts[tj][k];
            sr += a.x * b.x - a.y * b.y;
            si += a.x * b.y + a.y * b.x;
        }
        __syncthreads();
    }

    float sp, cp;
    __sincosf(phi_ext[i0 + ti], &sp, &cp);
    Wb[(size_t)(i0 + ti) * NN + j0 + tj] = f2bf(cp * sr - sp * si);
}

// ---------------- out = x @ Wb^T via MFMA bf16; x converted in staging ------
__global__ __launch_bounds__(256) void gemm_kernel(const float* __restrict__ x,
                                                   const unsigned short* __restrict__ Wb,
                                                   float* __restrict__ out) {
    __shared__ unsigned short Xs[64][72];
    __shared__ unsigned short Ws[64][72];

    const int tid = threadIdx.x;
    const int l   = tid & 63;
    const int wid = tid >> 6;
    const int wm  = wid >> 1, wn = wid & 1;
    const int b0  = blockIdx.x * 64;
    const int i0  = blockIdx.y * 64;

    const int srow = tid >> 2;            // staging: row 0..63
    const int sseg = (tid & 3) * 2;       // 2 of 8 8-elem segments

    f32x4 acc[2][2] = {{{0.f, 0.f, 0.f, 0.f}, {0.f, 0.f, 0.f, 0.f}},
                       {{0.f, 0.f, 0.f, 0.f}, {0.f, 0.f, 0.f, 0.f}}};

    const int fr = l & 15;
    const int kg = (l >> 4) * 8;

    for (int k0 = 0; k0 < NN; k0 += 64) {
        const float* xrow = x + (size_t)(b0 + srow) * NN + k0 + sseg * 8;
        float4 a = *(const float4*)(xrow);
        float4 b = *(const float4*)(xrow + 4);
        float4 c = *(const float4*)(xrow + 8);
        float4 d = *(const float4*)(xrow + 12);
        uint4 xv, xv2;
        xv.x  = (unsigned)f2bf(a.x) | ((unsigned)f2bf(a.y) << 16);
        xv.y  = (unsigned)f2bf(a.z) | ((unsigned)f2bf(a.w) << 16);
        xv.z  = (unsigned)f2bf(b.x) | ((unsigned)f2bf(b.y) << 16);
        xv.w  = (unsigned)f2bf(b.z) | ((unsigned)f2bf(b.w) << 16);
        xv2.x = (unsigned)f2bf(c.x) | ((unsigned)f2bf(c.y) << 16);
        xv2.y = (unsigned)f2bf(c.z) | ((unsigned)f2bf(c.w) << 16);
        xv2.z = (unsigned)f2bf(d.x) | ((unsigned)f2bf(d.y) << 16);
        xv2.w = (unsigned)f2bf(d.z) | ((unsigned)f2bf(d.w) << 16);
        uint4 wv  = *(const uint4*)(Wb + (size_t)(i0 + srow) * NN + k0 + sseg * 8);
        uint4 wv2 = *(const uint4*)(Wb + (size_t)(i0 + srow) * NN + k0 + (sseg + 1) * 8);
        *(uint4*)&Xs[srow][sseg * 8]       = xv;
        *(uint4*)&Ws[srow][sseg * 8]       = wv;
        *(uint4*)&Xs[srow][(sseg + 1) * 8] = xv2;
        *(uint4*)&Ws[srow][(sseg + 1) * 8] = wv2;
        __syncthreads();

#pragma unroll
        for (int ks = 0; ks < 2; ++ks) {
            bf16x8 a0  = *(const bf16x8*)&Xs[wm * 32 + fr][ks * 32 + kg];
            bf16x8 a1  = *(const bf16x8*)&Xs[wm * 32 + 16 + fr][ks * 32 + kg];
            bf16x8 bb0 = *(const bf16x8*)&Ws[wn * 32 + fr][ks * 32 + kg];
            bf16x8 bb1 = *(const bf16x8*)&Ws[wn * 32 + 16 + fr][ks * 32 + kg];
            acc[0][0] = __builtin_amdgcn_mfma_f32_16x16x32_bf16(a0, bb0, acc[0][0], 0, 0, 0);
            acc[0][1] = __builtin_amdgcn_mfma_f32_16x16x32_bf16(a0, bb1, acc[0][1], 0, 0, 0);
            acc[1][0] = __builtin_amdgcn_mfma_f32_16x16x32_bf16(a1, bb0, acc[1][0], 0, 0, 0);
            acc[1][1] = __builtin_amdgcn_mfma_f32_16x16x32_bf16(a1, bb1, acc[1][1], 0, 0, 0);
        }
        __syncthreads();
    }

    // D layout: col = l&15, row = (l>>4)*4 + reg   [m89-verified]
    const int drow = (l >> 4) * 4;
    const int dcol = l & 15;
#pragma unroll
    for (int mf = 0; mf < 2; ++mf)
#pragma unroll
        for (int nf = 0; nf < 2; ++nf) {
            float* op = out + (size_t)(b0 + wm * 32 + mf * 16 + drow) * NN
                      + i0 + wn * 32 + nf * 16 + dcol;
#pragma unroll
            for (int r = 0; r < 4; ++r) op[(size_t)r * NN] = acc[mf][nf][r];
        }
}

extern "C" void kernel_launch(void* const* d_in, const int* in_sizes, int n_in,
                              void* d_out, int out_size, void* d_ws, size_t ws_size,
                              hipStream_t stream) {
    const float* x     = (const float*)d_in[0];
    const float* theta = (const float*)d_in[1];
    const float* phi_i = (const float*)d_in[2];
    const float* phi_e = (const float*)d_in[3];
    float* out = (float*)d_out;

    float2* At  = (float2*)((char*)d_ws + WS_AT_OFF);
    float2* Bt  = (float2*)((char*)d_ws + WS_BT_OFF);
    f32x4*  cf3 = (f32x4*)((char*)d_ws + WS_CF_OFF);
    unsigned short* Wb = (unsigned short*)((char*)d_ws + WS_WB_OFF);

    coeff2_kernel<<<dim3(512), dim3(64), 0, stream>>>(theta, phi_i, cf3);
    build_kernel<<<dim3(256, 2), dim3(64), 0, stream>>>(cf3, At, Bt);
    mergebf_kernel<<<dim3(16, 16), dim3(256), 0, stream>>>(At, Bt, phi_e, Wb);
    gemm_kernel<<<dim3(NB / 64, NN / 64), dim3(256), 0, stream>>>(x, Wb, out);
}